// Round 1
// baseline (1249.402 us; speedup 1.0000x reference)
//
#include <hip/hip_runtime.h>

#define T_DIM 1024
#define B_DIM 128
#define L_DIM 128

// ---------------------------------------------------------------------------
// Denominator: forward algorithm. One block per batch, thread j owns state j.
// score[j] is kept in a register; per step:
//   m  = max_j score[j]                (wave shfl + cross-wave LDS)
//   es = exp(score - m)  -> LDS
//   acc_j = sum_i es[i] * etrans[i][j] (etrans column in 128 VGPRs, pure FMA)
//   new_j = m + log(acc_j) + pred[t,b,j];  if mask: score = new
// ---------------------------------------------------------------------------
__global__ __launch_bounds__(128, 1)
void crf_den_kernel(const float* __restrict__ pred,
                    const int*   __restrict__ mask,
                    const float* __restrict__ trans,
                    const float* __restrict__ start_s,
                    const float* __restrict__ end_s,
                    float* __restrict__ den_out)
{
    const int b    = blockIdx.x;
    const int j    = threadIdx.x;
    const int wave = j >> 6;
    const int lane = j & 63;

    // exp(transitions) column j in registers (static indices after unroll)
    float etr[L_DIM];
#pragma unroll
    for (int i = 0; i < L_DIM; ++i) {
        etr[i] = __expf(trans[i * L_DIM + j]);
    }

    __shared__ float es_lds[2][L_DIM];
    __shared__ float red_lds[2][2];

    float score = start_s[j] + pred[b * L_DIM + j];   // t = 0

    // prefetch t = 1
    float p_next = pred[(1 * B_DIM + b) * L_DIM + j];
    int   m_next = mask[1 * B_DIM + b];

    for (int t = 1; t < T_DIM; ++t) {
        const float p_cur = p_next;
        const int   mk    = m_next;
        if (t + 1 < T_DIM) {
            p_next = pred[((t + 1) * B_DIM + b) * L_DIM + j];
            m_next = mask[(t + 1) * B_DIM + b];
        }
        const int buf = t & 1;

        // block-wide max of score
        float wm = score;
#pragma unroll
        for (int off = 32; off >= 1; off >>= 1)
            wm = fmaxf(wm, __shfl_xor(wm, off, 64));
        if (lane == 0) red_lds[buf][wave] = wm;
        __syncthreads();
        const float m = fmaxf(red_lds[buf][0], red_lds[buf][1]);

        const float es = __expf(score - m);
        es_lds[buf][j] = es;
        __syncthreads();

        // acc = sum_i es[i] * etr[i]   (es via broadcast float4 LDS reads)
        const float* esb = es_lds[buf];
        float a0 = 0.f, a1 = 0.f, a2 = 0.f, a3 = 0.f;
#pragma unroll
        for (int i = 0; i < L_DIM; i += 4) {
            const float4 e4 = *(const float4*)&esb[i];
            a0 = fmaf(e4.x, etr[i + 0], a0);
            a1 = fmaf(e4.y, etr[i + 1], a1);
            a2 = fmaf(e4.z, etr[i + 2], a2);
            a3 = fmaf(e4.w, etr[i + 3], a3);
        }
        const float acc = (a0 + a1) + (a2 + a3);
        const float ns  = m + __logf(acc) + p_cur;
        if (mk) score = ns;
    }

    // den[b] = LSE_j(score[j] + end_s[j])
    float v  = score + end_s[j];
    float wm = v;
#pragma unroll
    for (int off = 32; off >= 1; off >>= 1)
        wm = fmaxf(wm, __shfl_xor(wm, off, 64));
    if (lane == 0) red_lds[0][wave] = wm;
    __syncthreads();
    const float m = fmaxf(red_lds[0][0], red_lds[0][1]);
    float e = __expf(v - m);
#pragma unroll
    for (int off = 32; off >= 1; off >>= 1)
        e += __shfl_xor(e, off, 64);
    if (lane == 0) red_lds[1][wave] = e;
    __syncthreads();
    if (j == 0) {
        den_out[b] = m + __logf(red_lds[1][0] + red_lds[1][1]);
    }
}

// ---------------------------------------------------------------------------
// Numerator: parallel over t within a block per batch.
// ---------------------------------------------------------------------------
__global__ __launch_bounds__(256, 1)
void crf_num_kernel(const float* __restrict__ pred,
                    const int*   __restrict__ targets,
                    const int*   __restrict__ mask,
                    const float* __restrict__ trans,
                    const float* __restrict__ start_s,
                    const float* __restrict__ end_s,
                    float* __restrict__ num_out)
{
    const int b = blockIdx.x;
    const int k = threadIdx.x;

    float local = 0.f;
    int   msum  = 0;
    for (int t = k; t < T_DIM; t += 256) {
        const int mk = mask[t * B_DIM + b];
        msum += mk;
        if (t >= 1) {
            const int tp = targets[(t - 1) * B_DIM + b];
            const int tc = targets[t * B_DIM + b];
            const float c = trans[tp * L_DIM + tc] +
                            pred[(t * B_DIM + b) * L_DIM + tc];
            local += c * (float)mk;
        }
    }

#pragma unroll
    for (int off = 32; off >= 1; off >>= 1) {
        local += __shfl_xor(local, off, 64);
        msum  += __shfl_xor(msum,  off, 64);
    }
    __shared__ float sred[4];
    __shared__ int   ired[4];
    const int w = k >> 6;
    if ((k & 63) == 0) { sred[w] = local; ired[w] = msum; }
    __syncthreads();
    if (k == 0) {
        float tot = sred[0] + sred[1] + sred[2] + sred[3];
        const int ms = ired[0] + ired[1] + ired[2] + ired[3];
        const int t0 = targets[b];                       // targets[0, b]
        tot += start_s[t0] + pred[b * L_DIM + t0];       // start + emit[0]
        const int last = ms - 1;
        tot += end_s[targets[last * B_DIM + b]];
        num_out[b] = tot;
    }
}

// ---------------------------------------------------------------------------
// Final: out = mean_b(den[b] - num[b])
// ---------------------------------------------------------------------------
__global__ __launch_bounds__(128, 1)
void crf_reduce_kernel(const float* __restrict__ den,
                       const float* __restrict__ num,
                       float* __restrict__ out)
{
    const int j = threadIdx.x;
    float d = den[j] - num[j];
#pragma unroll
    for (int off = 32; off >= 1; off >>= 1)
        d += __shfl_xor(d, off, 64);
    __shared__ float s[2];
    if ((j & 63) == 0) s[j >> 6] = d;
    __syncthreads();
    if (j == 0) out[0] = (s[0] + s[1]) * (1.0f / (float)B_DIM);
}

extern "C" void kernel_launch(void* const* d_in, const int* in_sizes, int n_in,
                              void* d_out, int out_size, void* d_ws, size_t ws_size,
                              hipStream_t stream)
{
    const float* pred    = (const float*)d_in[0];
    const int*   targets = (const int*)  d_in[1];
    const int*   mask    = (const int*)  d_in[2];
    const float* trans   = (const float*)d_in[3];
    const float* start_s = (const float*)d_in[4];
    const float* end_s   = (const float*)d_in[5];
    float* out = (float*)d_out;

    float* den = (float*)d_ws;
    float* num = den + B_DIM;

    crf_den_kernel<<<B_DIM, 128, 0, stream>>>(pred, mask, trans, start_s, end_s, den);
    crf_num_kernel<<<B_DIM, 256, 0, stream>>>(pred, targets, mask, trans, start_s, end_s, num);
    crf_reduce_kernel<<<1, 128, 0, stream>>>(den, num, out);
}

// Round 2
// 782.578 us; speedup vs baseline: 1.5965x; 1.5965x over previous
//
#include <hip/hip_runtime.h>

#define T_DIM 1024
#define B_DIM 128
#define L_DIM 128

__device__ __forceinline__ float readlane0_f32(float v) {
    return __uint_as_float(__builtin_amdgcn_readfirstlane(__float_as_uint(v)));
}

// ---------------------------------------------------------------------------
// Denominator: forward algorithm. One block (256 thr = 4 waves) per batch.
// Layout: wave w owns states [w*32, w*32+32); lane = (kh<<5)|sub where
// sub = state-within-wave, kh = k-half. Lane computes the partial dot
// acc[state] over i in [kh*64, kh*64+64), combined via shfl_xor(32).
// Shift trick: es computed with wave-local c_w = score[state w*32]
// (readfirstlane, no reduce); reconciled after the barrier by scaling
// partial sums with exp(c_w - max_w c_w). One barrier per step,
// double-buffered es.
// ---------------------------------------------------------------------------
__global__ __launch_bounds__(256, 1)
void crf_den_kernel(const float* __restrict__ pred,
                    const int*   __restrict__ mask,
                    const float* __restrict__ trans,
                    const float* __restrict__ start_s,
                    const float* __restrict__ end_s,
                    float* __restrict__ den_out)
{
    const int b     = blockIdx.x;
    const int tid   = threadIdx.x;
    const int w     = tid >> 6;         // wave 0..3
    const int lane  = tid & 63;
    const int sub   = lane & 31;        // state within wave
    const int kh    = lane >> 5;        // k-half (0: i=0..63, 1: i=64..127)
    const int state = w * 32 + sub;     // this lane's output state
    const int kbase = kh * 64;

    // etr[ii] = exp(trans[kbase+ii][state]) in registers (static idx)
    float etr[64];
#pragma unroll
    for (int ii = 0; ii < 64; ++ii)
        etr[ii] = __expf(trans[(kbase + ii) * L_DIM + state]);

    __shared__ __align__(16) float es_lds[2][L_DIM];
    __shared__ __align__(16) float c_lds[2][4];

    // t = 0
    float score = start_s[state] + pred[b * L_DIM + state];

    // prefetch t = 1
    float p_next = pred[(1 * B_DIM + b) * L_DIM + state];
    int   m_next = mask[1 * B_DIM + b];

    for (int t = 1; t < T_DIM; ++t) {
        const float p_cur = p_next;
        const int   mk    = m_next;
        if (t + 1 < T_DIM) {
            p_next = pred[((t + 1) * B_DIM + b) * L_DIM + state];
            m_next = mask[(t + 1) * B_DIM + b];
        }
        const int buf = t & 1;

        // wave-local shift (no reduction): score of state w*32 (lane 0)
        const float c_w = readlane0_f32(score);
        const float es  = __expf(score - c_w);
        if (lane < 32) es_lds[buf][state] = es;
        if (lane == 0) c_lds[buf][w] = c_w;
        __syncthreads();

        // partial matvec over this lane's k-range, split into the two
        // 32-wide owner sub-ranges so per-owner scaling can be applied
        const float* esb = &es_lds[buf][kbase];
        float a0 = 0.f, a1 = 0.f, a2 = 0.f, a3 = 0.f;
#pragma unroll
        for (int ii = 0; ii < 32; ii += 4) {
            const float4 e4 = *(const float4*)&esb[ii];
            a0 = fmaf(e4.x, etr[ii + 0], a0);
            a1 = fmaf(e4.y, etr[ii + 1], a1);
            a0 = fmaf(e4.z, etr[ii + 2], a0);
            a1 = fmaf(e4.w, etr[ii + 3], a1);
        }
#pragma unroll
        for (int ii = 32; ii < 64; ii += 4) {
            const float4 e4 = *(const float4*)&esb[ii];
            a2 = fmaf(e4.x, etr[ii + 0], a2);
            a3 = fmaf(e4.y, etr[ii + 1], a3);
            a2 = fmaf(e4.z, etr[ii + 2], a2);
            a3 = fmaf(e4.w, etr[ii + 3], a3);
        }

        // reconcile wave-local shifts (c read latency hidden behind FMAs)
        const float4 cv = *(const float4*)&c_lds[buf][0];
        const float c   = fmaxf(fmaxf(cv.x, cv.y), fmaxf(cv.z, cv.w));
        const float cA  = (kh == 0) ? cv.x : cv.z;   // owner of i in [kbase, kbase+32)
        const float cB  = (kh == 0) ? cv.y : cv.w;   // owner of i in [kbase+32, kbase+64)
        const float fA  = __expf(cA - c);
        const float fB  = __expf(cB - c);

        const float part = fA * (a0 + a1) + fB * (a2 + a3);
        const float acc  = part + __shfl_xor(part, 32, 64);

        const float ns = c + __logf(acc) + p_cur;
        if (mk) score = ns;
    }

    // final LSE over states: v duplicated in both k-halves of each wave,
    // so a 64-lane sum double-counts -> multiply by 0.5 at the end.
    const float v = score + end_s[state];
    float wm = v;
#pragma unroll
    for (int off = 32; off >= 1; off >>= 1)
        wm = fmaxf(wm, __shfl_xor(wm, off, 64));
    float e = __expf(v - wm);
#pragma unroll
    for (int off = 32; off >= 1; off >>= 1)
        e += __shfl_xor(e, off, 64);
    if (lane == 0) { c_lds[0][w] = wm; c_lds[1][w] = e; }
    __syncthreads();
    if (tid == 0) {
        const float m0 = fmaxf(fmaxf(c_lds[0][0], c_lds[0][1]),
                               fmaxf(c_lds[0][2], c_lds[0][3]));
        float s = 0.f;
#pragma unroll
        for (int ww = 0; ww < 4; ++ww)
            s += c_lds[1][ww] * __expf(c_lds[0][ww] - m0);
        den_out[b] = m0 + __logf(s * 0.5f);
    }
}

// ---------------------------------------------------------------------------
// Numerator: parallel over t within a block per batch.
// ---------------------------------------------------------------------------
__global__ __launch_bounds__(256, 1)
void crf_num_kernel(const float* __restrict__ pred,
                    const int*   __restrict__ targets,
                    const int*   __restrict__ mask,
                    const float* __restrict__ trans,
                    const float* __restrict__ start_s,
                    const float* __restrict__ end_s,
                    float* __restrict__ num_out)
{
    const int b = blockIdx.x;
    const int k = threadIdx.x;

    float local = 0.f;
    int   msum  = 0;
    for (int t = k; t < T_DIM; t += 256) {
        const int mk = mask[t * B_DIM + b];
        msum += mk;
        if (t >= 1) {
            const int tp = targets[(t - 1) * B_DIM + b];
            const int tc = targets[t * B_DIM + b];
            const float c = trans[tp * L_DIM + tc] +
                            pred[(t * B_DIM + b) * L_DIM + tc];
            local += c * (float)mk;
        }
    }

#pragma unroll
    for (int off = 32; off >= 1; off >>= 1) {
        local += __shfl_xor(local, off, 64);
        msum  += __shfl_xor(msum,  off, 64);
    }
    __shared__ float sred[4];
    __shared__ int   ired[4];
    const int w = k >> 6;
    if ((k & 63) == 0) { sred[w] = local; ired[w] = msum; }
    __syncthreads();
    if (k == 0) {
        float tot = sred[0] + sred[1] + sred[2] + sred[3];
        const int ms = ired[0] + ired[1] + ired[2] + ired[3];
        const int t0 = targets[b];                       // targets[0, b]
        tot += start_s[t0] + pred[b * L_DIM + t0];       // start + emit[0]
        const int last = ms - 1;
        tot += end_s[targets[last * B_DIM + b]];
        num_out[b] = tot;
    }
}

// ---------------------------------------------------------------------------
// Final: out = mean_b(den[b] - num[b])
// ---------------------------------------------------------------------------
__global__ __launch_bounds__(128, 1)
void crf_reduce_kernel(const float* __restrict__ den,
                       const float* __restrict__ num,
                       float* __restrict__ out)
{
    const int j = threadIdx.x;
    float d = den[j] - num[j];
#pragma unroll
    for (int off = 32; off >= 1; off >>= 1)
        d += __shfl_xor(d, off, 64);
    __shared__ float s[2];
    if ((j & 63) == 0) s[j >> 6] = d;
    __syncthreads();
    if (j == 0) out[0] = (s[0] + s[1]) * (1.0f / (float)B_DIM);
}

extern "C" void kernel_launch(void* const* d_in, const int* in_sizes, int n_in,
                              void* d_out, int out_size, void* d_ws, size_t ws_size,
                              hipStream_t stream)
{
    const float* pred    = (const float*)d_in[0];
    const int*   targets = (const int*)  d_in[1];
    const int*   mask    = (const int*)  d_in[2];
    const float* trans   = (const float*)d_in[3];
    const float* start_s = (const float*)d_in[4];
    const float* end_s   = (const float*)d_in[5];
    float* out = (float*)d_out;

    float* den = (float*)d_ws;
    float* num = den + B_DIM;

    crf_den_kernel<<<B_DIM, 256, 0, stream>>>(pred, mask, trans, start_s, end_s, den);
    crf_num_kernel<<<B_DIM, 256, 0, stream>>>(pred, targets, mask, trans, start_s, end_s, num);
    crf_reduce_kernel<<<1, 128, 0, stream>>>(den, num, out);
}

// Round 3
// 735.739 us; speedup vs baseline: 1.6982x; 1.0637x over previous
//
#include <hip/hip_runtime.h>
#include <math.h>

#define T_DIM 1024
#define B_DIM 128
#define L_DIM 128

__device__ __forceinline__ float readlane0_f32(float v) {
    return __uint_as_float(__builtin_amdgcn_readfirstlane(__float_as_uint(v)));
}

// ---------------------------------------------------------------------------
// Denominator, exp-domain forward recursion. One block (512 thr = 8 waves)
// per batch. Wave w owns states [16w,16w+16); lane = (kq<<4)|sub computes
// the partial dot for state over k in [32kq,32kq+32), combined via 2 shfl.
//
// Representation: score_j = log(u_j) + D*ln2, D uniform across block.
// Per step (no exp/log on the chain):
//   E_w   = exponent(u[16w])        (readfirstlane + bit ops)
//   us    = u * 2^-E_w              -> LDS (4 bank-staggered copies)
//   raw-barrier (lgkmcnt only -- global prefetch stays in flight!)
//   accA/B = sum us*etr per 16-wide writer block  (pure FMA, reg etr)
//   part  = ldexp(accA, eA-emax) + ldexp(accB, eB-emax); combine kq via shfl
//   u'    = acc * ep_t   (ep = exp(pred) prefetched/computed 2 steps early)
//   D    += emax
// ---------------------------------------------------------------------------
__global__ __launch_bounds__(512, 1)
void crf_den_kernel(const float* __restrict__ pred,
                    const int*   __restrict__ mask,
                    const float* __restrict__ trans,
                    const float* __restrict__ start_s,
                    const float* __restrict__ end_s,
                    float* __restrict__ den_out)
{
    const int b     = blockIdx.x;
    const int tid   = threadIdx.x;
    const int w     = tid >> 6;          // wave 0..7
    const int lane  = tid & 63;
    const int sub   = lane & 15;         // state-within-wave
    const int kq    = lane >> 4;         // k-quarter 0..3
    const int state = w * 16 + sub;
    const int kbase = kq * 32;

    // etr[ii] = exp(trans[kbase+ii][state]), compile-time reg indices
    float etr[32];
#pragma unroll
    for (int ii = 0; ii < 32; ++ii)
        etr[ii] = __expf(trans[(kbase + ii) * L_DIM + state]);

    // 4 copies of the 128-float es vector, copy c at word offset c*132:
    // reader kq reads copy kq at word 164*kq + 4c -> bank 4kq+4c, conflict-free
    __shared__ __align__(16) float es_lds[2][4 * 132];
    __shared__ __align__(16) int   e_lds[2][8];
    __shared__ float fsum_lds[8];

    float u = __expf(start_s[state] + pred[b * L_DIM + state]);  // t=0
    int   D = 0;

    // prefetch pipeline (2 steps deep):
    float ep_next = __expf(pred[(1 * B_DIM + b) * L_DIM + state]); // step 1
    float p2      = pred[(2 * B_DIM + b) * L_DIM + state];         // step 2 raw
    int   mk_next = mask[1 * B_DIM + b];
    int   mk2     = mask[2 * B_DIM + b];

    for (int t = 1; t < T_DIM; ++t) {
        const float ep_cur = ep_next;
        const int   mk     = mk_next;
        // issue loads for t+2; they stay in flight across the raw barrier
        const int tpre = (t + 2 < T_DIM) ? (t + 2) : (T_DIM - 1);
        const float p3  = pred[(tpre * B_DIM + b) * L_DIM + state];
        const int   mk3 = mask[tpre * B_DIM + b];
        ep_next = __expf(p2);          // for step t+1 (loaded 2 iters ago)
        p2 = p3; mk_next = mk2; mk2 = mk3;

        const int buf = t & 1;

        // ---- writer phase: per-wave exponent normalization ----
        const unsigned ub      = __float_as_uint(readlane0_f32(u));
        const int      Ebiased = (int)(ub >> 23);            // u > 0 always
        const float    scale   = __uint_as_float((unsigned)(254 - Ebiased) << 23); // 2^-E
        const float    us      = u * scale;
        if (lane < 16) {
            float* dst = &es_lds[buf][state];
#pragma unroll
            for (int c = 0; c < 4; ++c) dst[c * 132] = us;
        }
        if (lane == 0) e_lds[buf][w] = Ebiased;

        asm volatile("s_waitcnt lgkmcnt(0)" ::: "memory");
        __builtin_amdgcn_s_barrier();
        __builtin_amdgcn_sched_barrier(0);

        // ---- reader phase ----
        const float* esb = &es_lds[buf][kq * 132 + kbase];
        const int4  eL = *(const int4*)&e_lds[buf][0];
        const int4  eH = *(const int4*)&e_lds[buf][4];

        float accA = 0.f, accB = 0.f;
#pragma unroll
        for (int c = 0; c < 4; ++c) {
            const float4 e4 = *(const float4*)&esb[c * 4];
            accA = fmaf(e4.x, etr[c * 4 + 0], accA);
            accA = fmaf(e4.y, etr[c * 4 + 1], accA);
            accA = fmaf(e4.z, etr[c * 4 + 2], accA);
            accA = fmaf(e4.w, etr[c * 4 + 3], accA);
        }
#pragma unroll
        for (int c = 4; c < 8; ++c) {
            const float4 e4 = *(const float4*)&esb[c * 4];
            accB = fmaf(e4.x, etr[c * 4 + 0], accB);
            accB = fmaf(e4.y, etr[c * 4 + 1], accB);
            accB = fmaf(e4.z, etr[c * 4 + 2], accB);
            accB = fmaf(e4.w, etr[c * 4 + 3], accB);
        }

        // exponent reconciliation (biased ints; differences are unbiased)
        const int emax = max(max(max(eL.x, eL.y), max(eL.z, eL.w)),
                             max(max(eH.x, eH.y), max(eH.z, eH.w)));
        int eA, eB;
        switch (kq) {   // writer-wave exponents for this lane's two 16-blocks
            case 0: eA = eL.x; eB = eL.y; break;
            case 1: eA = eL.z; eB = eL.w; break;
            case 2: eA = eH.x; eB = eH.y; break;
            default: eA = eH.z; eB = eH.w; break;
        }
        float part = ldexpf(accA, eA - emax) + ldexpf(accB, eB - emax);
        part += __shfl_xor(part, 16, 64);
        part += __shfl_xor(part, 32, 64);

        if (mk) { u = part * ep_cur; D += (emax - 127); }
    }

    // ---- final LSE over states ----
    float val = (kq == 0) ? u * __expf(end_s[state]) : 0.f;
#pragma unroll
    for (int off = 32; off >= 1; off >>= 1)
        val += __shfl_xor(val, off, 64);
    if (lane == 0) fsum_lds[w] = val;
    __syncthreads();
    if (tid == 0) {
        float tot = 0.f;
#pragma unroll
        for (int ww = 0; ww < 8; ++ww) tot += fsum_lds[ww];
        den_out[b] = logf(tot) + (float)D * 0.69314718055994531f;
    }
}

// ---------------------------------------------------------------------------
// Numerator: parallel over t within a block per batch.
// ---------------------------------------------------------------------------
__global__ __launch_bounds__(256, 1)
void crf_num_kernel(const float* __restrict__ pred,
                    const int*   __restrict__ targets,
                    const int*   __restrict__ mask,
                    const float* __restrict__ trans,
                    const float* __restrict__ start_s,
                    const float* __restrict__ end_s,
                    float* __restrict__ num_out)
{
    const int b = blockIdx.x;
    const int k = threadIdx.x;

    float local = 0.f;
    int   msum  = 0;
    for (int t = k; t < T_DIM; t += 256) {
        const int mk = mask[t * B_DIM + b];
        msum += mk;
        if (t >= 1) {
            const int tp = targets[(t - 1) * B_DIM + b];
            const int tc = targets[t * B_DIM + b];
            const float c = trans[tp * L_DIM + tc] +
                            pred[(t * B_DIM + b) * L_DIM + tc];
            local += c * (float)mk;
        }
    }

#pragma unroll
    for (int off = 32; off >= 1; off >>= 1) {
        local += __shfl_xor(local, off, 64);
        msum  += __shfl_xor(msum,  off, 64);
    }
    __shared__ float sred[4];
    __shared__ int   ired[4];
    const int w = k >> 6;
    if ((k & 63) == 0) { sred[w] = local; ired[w] = msum; }
    __syncthreads();
    if (k == 0) {
        float tot = sred[0] + sred[1] + sred[2] + sred[3];
        const int ms = ired[0] + ired[1] + ired[2] + ired[3];
        const int t0 = targets[b];                       // targets[0, b]
        tot += start_s[t0] + pred[b * L_DIM + t0];       // start + emit[0]
        const int last = ms - 1;
        tot += end_s[targets[last * B_DIM + b]];
        num_out[b] = tot;
    }
}

// ---------------------------------------------------------------------------
// Final: out = mean_b(den[b] - num[b])
// ---------------------------------------------------------------------------
__global__ __launch_bounds__(128, 1)
void crf_reduce_kernel(const float* __restrict__ den,
                       const float* __restrict__ num,
                       float* __restrict__ out)
{
    const int j = threadIdx.x;
    float d = den[j] - num[j];
#pragma unroll
    for (int off = 32; off >= 1; off >>= 1)
        d += __shfl_xor(d, off, 64);
    __shared__ float s[2];
    if ((j & 63) == 0) s[j >> 6] = d;
    __syncthreads();
    if (j == 0) out[0] = (s[0] + s[1]) * (1.0f / (float)B_DIM);
}

extern "C" void kernel_launch(void* const* d_in, const int* in_sizes, int n_in,
                              void* d_out, int out_size, void* d_ws, size_t ws_size,
                              hipStream_t stream)
{
    const float* pred    = (const float*)d_in[0];
    const int*   targets = (const int*)  d_in[1];
    const int*   mask    = (const int*)  d_in[2];
    const float* trans   = (const float*)d_in[3];
    const float* start_s = (const float*)d_in[4];
    const float* end_s   = (const float*)d_in[5];
    float* out = (float*)d_out;

    float* den = (float*)d_ws;
    float* num = den + B_DIM;

    crf_den_kernel<<<B_DIM, 512, 0, stream>>>(pred, mask, trans, start_s, end_s, den);
    crf_num_kernel<<<B_DIM, 256, 0, stream>>>(pred, targets, mask, trans, start_s, end_s, num);
    crf_reduce_kernel<<<1, 128, 0, stream>>>(den, num, out);
}